// Round 3
// baseline (659.692 us; speedup 1.0000x reference)
//
#include <hip/hip_runtime.h>

#define HT 64
#define WT 64
#define CT 256
#define KDIM 2304   // 256 channels * 9 taps
#define MT 128      // o-tile
#define KC 36       // k-chunk: 4 channels * 9 taps
#define WPAD 38     // padded LDS row for W tile

// Precompute bilinear sample coords + corner weights for one (b,h) row into LDS.
// Corner validity (zero-pad outside) folded into weights; indices clamped.
__device__ __forceinline__ void precompute_coords(const float* __restrict__ off, int b, int h, int tid,
                                                  float4 (*s_wt)[64], int2 (*s_off)[64])
{
    for (int e = tid; e < 9 * 64; e += 256) {
        int kk = e >> 6, w = e & 63;
        int ky = kk / 3, kx = kk - ky * 3;
        float dy = off[((size_t)(b * 18 + 2 * kk) * 64 + h) * 64 + w];
        float dx = off[((size_t)(b * 18 + 2 * kk + 1) * 64 + h) * 64 + w];
        float py = (float)(h + ky - 1) + dy;
        float px = (float)(w + kx - 1) + dx;
        float y0f = floorf(py), x0f = floorf(px);
        int y0 = (int)y0f, x0 = (int)x0f;
        float fy = py - y0f, fx = px - x0f;
        float vy0 = (y0 >= 0 && y0 < HT) ? 1.f : 0.f;
        float vy1 = (y0 >= -1 && y0 < HT - 1) ? 1.f : 0.f;
        float vx0 = (x0 >= 0 && x0 < WT) ? 1.f : 0.f;
        float vx1 = (x0 >= -1 && x0 < WT - 1) ? 1.f : 0.f;
        float4 wt;
        wt.x = (1.f - fy) * (1.f - fx) * vy0 * vx0;
        wt.y = (1.f - fy) * fx * vy0 * vx1;
        wt.z = fy * (1.f - fx) * vy1 * vx0;
        wt.w = fy * fx * vy1 * vx1;
        int yc0 = min(max(y0, 0), HT - 1), yc1 = min(max(y0 + 1, 0), HT - 1);
        int xc0 = min(max(x0, 0), WT - 1), xc1 = min(max(x0 + 1, 0), WT - 1);
        s_wt[kk][w] = wt;
        s_off[kk][w] = make_int2((yc0 * WT + xc0) | ((yc0 * WT + xc1) << 16),
                                 (yc1 * WT + xc0) | ((yc1 * WT + xc1) << 16));
    }
}

// Kernel 1: channel attention gate. One block per (b,h) row.
// thread = (q, p): q = channel quarter (4 x 64 channels), p = w position.
__global__ __launch_bounds__(256) void k_att(const float* __restrict__ x, const float* __restrict__ off,
                                             const float* __restrict__ att_w, const float* __restrict__ att_b,
                                             float* __restrict__ att_out)
{
    __shared__ float4 s_wt[9][64];
    __shared__ int2 s_off[9][64];
    __shared__ float s_part[4][64];
    int blk = blockIdx.x;          // b*64 + h
    int b = blk >> 6, h = blk & 63;
    int tid = threadIdx.x;
    precompute_coords(off, b, h, tid, s_wt, s_off);
    __syncthreads();

    int p = tid & 63, q = tid >> 6;
    const float* xb = x + (size_t)(b * CT + q * 64) * 4096;
    float acc = 0.f;
    for (int ci = 0; ci < 64; ++ci) {
        const float* xc = xb + (size_t)ci * 4096;
        float m = -1e30f;
#pragma unroll
        for (int kk = 0; kk < 9; ++kk) {
            float4 wt = s_wt[kk][p];
            int2 of = s_off[kk][p];
            float v = wt.x * xc[of.x & 0xffff] + wt.y * xc[(of.x >> 16) & 0xffff]
                    + wt.z * xc[of.y & 0xffff] + wt.w * xc[(of.y >> 16) & 0xffff];
            m = fmaxf(m, v);
        }
        acc += att_w[q * 64 + ci] * m;
    }
    s_part[q][p] = acc;
    __syncthreads();
    if (tid < 64) {
        float s = s_part[0][tid] + s_part[1][tid] + s_part[2][tid] + s_part[3][tid] + att_b[0];
        att_out[(size_t)blk * 64 + tid] = 1.f / (1.f + expf(-s));
    }
}

// Kernel 2: fused deformable-unfold + GEMM. out_pre[b,o,h,w] = att[n] * sum_k W[o,k]*col[k,n]
// Block: 64 spatial (one (b,h) row) x 128 outputs. 256 threads, 8x4 accum per thread.
__global__ __launch_bounds__(256) void k_conv(const float* __restrict__ x, const float* __restrict__ off,
                                              const float* __restrict__ wgt, const float* __restrict__ att_in,
                                              float* __restrict__ outp)
{
    __shared__ float4 s_wt[9][64];
    __shared__ int2 s_off[9][64];
    __shared__ float s_att[64];
    __shared__ float s_W[MT][WPAD];
    __shared__ float s_col[KC][64];

    int blk = blockIdx.x;          // b*64 + h
    int b = blk >> 6, h = blk & 63;
    int o0 = blockIdx.y * MT;
    int tid = threadIdx.x;
    precompute_coords(off, b, h, tid, s_wt, s_off);
    if (tid < 64) s_att[tid] = att_in[(size_t)blk * 64 + tid];

    int tx = tid & 15, ty = tid >> 4;
    float acc[8][4];
#pragma unroll
    for (int i = 0; i < 8; ++i)
#pragma unroll
        for (int j = 0; j < 4; ++j) acc[i][j] = 0.f;

    const float* xbase = x + (size_t)b * CT * 4096;

    for (int ch = 0; ch < KDIM / KC; ++ch) {
        int k0 = ch * KC;
        int c0 = ch * 4;
        __syncthreads();
        // stage W chunk: 128 rows x 36 cols (as 18 float2 per row)
#pragma unroll
        for (int it = 0; it < 9; ++it) {
            int l = tid + it * 256;            // [0, 2304)
            int ol = l / 18, j2 = l - ol * 18;
            float2 u = *(const float2*)(wgt + (size_t)(o0 + ol) * KDIM + k0 + j2 * 2);
            s_W[ol][j2 * 2] = u.x;
            s_W[ol][j2 * 2 + 1] = u.y;
        }
        // stage col chunk: 36 x 64, bilinear gather from x
#pragma unroll
        for (int it = 0; it < 9; ++it) {
            int l = tid + it * 256;            // [0, 2304)
            int n = l & 63, j = l >> 6;        // j in [0,36)
            int c = c0 + j / 9;
            int kk = j - (j / 9) * 9;
            int2 of = s_off[kk][n];
            float4 wt = s_wt[kk][n];
            const float* xc = xbase + ((size_t)c << 12);
            float v = wt.x * xc[of.x & 0xffff] + wt.y * xc[(of.x >> 16) & 0xffff]
                    + wt.z * xc[of.y & 0xffff] + wt.w * xc[(of.y >> 16) & 0xffff];
            s_col[j][n] = v;
        }
        __syncthreads();
        // compute
#pragma unroll
        for (int j = 0; j < KC; ++j) {
            float4 bv = *(const float4*)&s_col[j][tx * 4];
            float a[8];
#pragma unroll
            for (int oi = 0; oi < 8; ++oi) a[oi] = s_W[ty * 8 + oi][j];
#pragma unroll
            for (int oi = 0; oi < 8; ++oi) {
                acc[oi][0] += a[oi] * bv.x;
                acc[oi][1] += a[oi] * bv.y;
                acc[oi][2] += a[oi] * bv.z;
                acc[oi][3] += a[oi] * bv.w;
            }
        }
    }
    __syncthreads();

    float av[4];
#pragma unroll
    for (int ni = 0; ni < 4; ++ni) av[ni] = s_att[tx * 4 + ni];
#pragma unroll
    for (int oi = 0; oi < 8; ++oi) {
        int o = o0 + ty * 8 + oi;
        size_t base = ((size_t)(b * CT + o) << 12) + h * 64 + tx * 4;
        float4 pk;
        pk.x = acc[oi][0] * av[0];
        pk.y = acc[oi][1] * av[1];
        pk.z = acc[oi][2] * av[2];
        pk.w = acc[oi][3] * av[3];
        *(float4*)(outp + base) = pk;
    }
}

// Kernel 3: GroupNorm stats. One block per (b,g) group = 32768 contiguous floats.
__global__ __launch_bounds__(256) void k_gnstats(const float* __restrict__ outp, float* __restrict__ stats)
{
    int bg = blockIdx.x;
    const float4* p4 = (const float4*)(outp + (size_t)bg * 32768);
    int tid = threadIdx.x;
    float s = 0.f, s2 = 0.f;
    for (int i = tid; i < 8192; i += 256) {
        float4 v = p4[i];
        s += (v.x + v.y) + (v.z + v.w);
        s2 += v.x * v.x + v.y * v.y + v.z * v.z + v.w * v.w;
    }
#pragma unroll
    for (int d = 32; d; d >>= 1) {
        s += __shfl_down(s, d);
        s2 += __shfl_down(s2, d);
    }
    __shared__ float rs[4], rs2[4];
    if ((tid & 63) == 0) { rs[tid >> 6] = s; rs2[tid >> 6] = s2; }
    __syncthreads();
    if (tid == 0) {
        float S = rs[0] + rs[1] + rs[2] + rs[3];
        float S2 = rs2[0] + rs2[1] + rs2[2] + rs2[3];
        float mean = S * (1.f / 32768.f);
        float var = S2 * (1.f / 32768.f) - mean * mean;
        stats[bg * 2] = mean;
        stats[bg * 2 + 1] = rsqrtf(var + 1e-5f);
    }
}

// Kernel 4: normalize + affine + ReLU, in place. 4 elems per thread (float4).
__global__ __launch_bounds__(256) void k_gnorm(float* __restrict__ outp, const float* __restrict__ stats,
                                               const float* __restrict__ gamma, const float* __restrict__ beta)
{
    int idx = blockIdx.x * 256 + threadIdx.x;      // [0, 1048576)
    size_t e = (size_t)idx * 4;
    int c = (int)((e >> 12) & 255);
    int bg = (int)(e >> 15);
    float mean = stats[bg * 2], rstd = stats[bg * 2 + 1];
    float ga = gamma[c], be = beta[c];
    float4 v = ((const float4*)outp)[idx];
    float4 r;
    r.x = fmaxf((v.x - mean) * rstd * ga + be, 0.f);
    r.y = fmaxf((v.y - mean) * rstd * ga + be, 0.f);
    r.z = fmaxf((v.z - mean) * rstd * ga + be, 0.f);
    r.w = fmaxf((v.w - mean) * rstd * ga + be, 0.f);
    ((float4*)outp)[idx] = r;
}

extern "C" void kernel_launch(void* const* d_in, const int* in_sizes, int n_in,
                              void* d_out, int out_size, void* d_ws, size_t ws_size,
                              hipStream_t stream)
{
    const float* x = (const float*)d_in[0];
    const float* off = (const float*)d_in[1];
    const float* wgt = (const float*)d_in[2];
    const float* attw = (const float*)d_in[3];
    const float* attb = (const float*)d_in[4];
    const float* gamma = (const float*)d_in[5];
    const float* beta = (const float*)d_in[6];
    float* outp = (float*)d_out;

    float* att = (float*)d_ws;          // 16384 floats
    float* stats = att + 16384;         // 256 floats

    k_att<<<dim3(256), dim3(256), 0, stream>>>(x, off, attw, attb, att);
    k_conv<<<dim3(256, 2), dim3(256), 0, stream>>>(x, off, wgt, att, outp);
    k_gnstats<<<dim3(128), dim3(256), 0, stream>>>(outp, stats);
    k_gnorm<<<dim3(4096), dim3(256), 0, stream>>>(outp, stats, gamma, beta);
}

// Round 4
// 353.688 us; speedup vs baseline: 1.8652x; 1.8652x over previous
//
#include <hip/hip_runtime.h>

#define CT 256
#define KDIM 2304    // 256 channels * 9 taps
#define NSTEP 72     // 2304 / 32

typedef __attribute__((ext_vector_type(8))) short bf16x8;
typedef __attribute__((ext_vector_type(4))) float f32x4;

// f32 -> bf16 bits, round-to-nearest-even (finite inputs only)
__device__ __forceinline__ unsigned f2b(float f) {
    unsigned u = __float_as_uint(f);
    u += 0x7fffu + ((u >> 16) & 1u);
    return u >> 16;
}

// Bilinear sample coords + corner weights for NW positions of one (b,h) row.
// Zero-pad validity folded into weights; indices clamped. s_wt/s_off are [9*NW].
template<int NW>
__device__ __forceinline__ void precompute_coords(const float* __restrict__ off, int b, int h, int w0,
                                                  int tid, float4* s_wt, int2* s_off)
{
    for (int e = tid; e < 9 * NW; e += 256) {
        int kk = e / NW, wl = e % NW;
        int w = w0 + wl;
        int ky = kk / 3, kx = kk - ky * 3;
        float dy = off[((size_t)(b * 18 + 2 * kk) * 64 + h) * 64 + w];
        float dx = off[((size_t)(b * 18 + 2 * kk + 1) * 64 + h) * 64 + w];
        float py = (float)(h + ky - 1) + dy;
        float px = (float)(w + kx - 1) + dx;
        float y0f = floorf(py), x0f = floorf(px);
        int y0 = (int)y0f, x0 = (int)x0f;
        float fy = py - y0f, fx = px - x0f;
        float vy0 = (y0 >= 0 && y0 < 64) ? 1.f : 0.f;
        float vy1 = (y0 >= -1 && y0 < 63) ? 1.f : 0.f;
        float vx0 = (x0 >= 0 && x0 < 64) ? 1.f : 0.f;
        float vx1 = (x0 >= -1 && x0 < 63) ? 1.f : 0.f;
        float4 wt;
        wt.x = (1.f - fy) * (1.f - fx) * vy0 * vx0;
        wt.y = (1.f - fy) * fx * vy0 * vx1;
        wt.z = fy * (1.f - fx) * vy1 * vx0;
        wt.w = fy * fx * vy1 * vx1;
        int yc0 = min(max(y0, 0), 63), yc1 = min(max(y0 + 1, 0), 63);
        int xc0 = min(max(x0, 0), 63), xc1 = min(max(x0 + 1, 0), 63);
        s_wt[kk * NW + wl] = wt;
        s_off[kk * NW + wl] = make_int2((yc0 * 64 + xc0) | ((yc0 * 64 + xc1) << 16),
                                        (yc1 * 64 + xc0) | ((yc1 * 64 + xc1) << 16));
    }
}

// Repack weight f32[256][2304] -> bf16, K-chunked (32) with k-block XOR-swizzle per m.
// Unit u (16B = 8 bf16): kc = u>>10, m = (u&1023)>>2, j = u&3; content k-block = j ^ ((m>>1)&3).
__global__ __launch_bounds__(256) void k_prep(const float* __restrict__ wgt, uint4* __restrict__ pw)
{
    int u = blockIdx.x * 256 + threadIdx.x;        // [0, 73728)
    int kc = u >> 10, r = u & 1023;
    int m = r >> 2, j = r & 3;
    int jj = j ^ ((m >> 1) & 3);
    const float* src = wgt + (size_t)m * KDIM + kc * 32 + jj * 8;
    float4 a = *(const float4*)src;
    float4 c = *(const float4*)(src + 4);
    uint4 o;
    o.x = f2b(a.x) | (f2b(a.y) << 16);
    o.y = f2b(a.z) | (f2b(a.w) << 16);
    o.z = f2b(c.x) | (f2b(c.y) << 16);
    o.w = f2b(c.z) | (f2b(c.w) << 16);
    pw[u] = o;
}

// Channel-attention partial dot. Grid 1024: (rowblk 0..255) x (channel group g 0..3).
// Thread (q=tid>>6, p=tid&63) handles 16 channels; partials -> ws (no bias/sigmoid here).
__global__ __launch_bounds__(256) void k_att(const float* __restrict__ x, const float* __restrict__ off,
                                             const float* __restrict__ att_w, float* __restrict__ att_part)
{
    __shared__ float4 s_wt[9 * 64];
    __shared__ int2 s_off[9 * 64];
    __shared__ float s_part[4][64];
    int rowblk = blockIdx.x & 255, g = blockIdx.x >> 8;
    int b = rowblk >> 6, h = rowblk & 63;
    int tid = threadIdx.x;
    precompute_coords<64>(off, b, h, 0, tid, s_wt, s_off);
    __syncthreads();

    int p = tid & 63, q = tid >> 6;
    int c0 = g * 64 + q * 16;
    const float* xb = x + ((size_t)(b * CT + c0) << 12);
    float acc = 0.f;
    for (int ci = 0; ci < 16; ++ci) {
        const float* xc = xb + ((size_t)ci << 12);
        float m = -1e30f;
#pragma unroll
        for (int kk = 0; kk < 9; ++kk) {
            float4 wt = s_wt[kk * 64 + p];
            int2 of = s_off[kk * 64 + p];
            float v = wt.x * xc[of.x & 0xffff] + wt.y * xc[(of.x >> 16) & 0xffff]
                    + wt.z * xc[of.y & 0xffff] + wt.w * xc[(of.y >> 16) & 0xffff];
            m = fmaxf(m, v);
        }
        acc += att_w[c0 + ci] * m;
    }
    s_part[q][p] = acc;
    __syncthreads();
    if (tid < 64)
        att_part[g * 16384 + rowblk * 64 + tid] =
            s_part[0][tid] + s_part[1][tid] + s_part[2][tid] + s_part[3][tid];
}

// Fused deformable-unfold + MFMA GEMM + attention epilogue.
// Grid 512: blockIdx.x = rowblk*2 + half. BM=256 (full M), BN=32, BK=32, 72 K-steps.
// 4 waves: wave w covers m in [w*64, w*64+64) x all 32 n. 4x2 MFMA 16x16x32 tiles/wave.
__global__ __launch_bounds__(256) void k_conv(const float* __restrict__ x, const float* __restrict__ off,
                                              const uint4* __restrict__ pw, const float* __restrict__ att_part,
                                              const float* __restrict__ att_b, float* __restrict__ outp)
{
    __shared__ float4 s_wt[9 * 32];
    __shared__ int2 s_off[9 * 32];
    __shared__ float s_att[32];
    __shared__ unsigned short Wl[256 * 32];   // 16 KB, row m = 32 bf16 (64B), k-block swizzled
    __shared__ unsigned short Cl[32 * 32];    // 2 KB, row n = 32 bf16, same swizzle

    int rowblk = blockIdx.x >> 1, half = blockIdx.x & 1;
    int b = rowblk >> 6, h = rowblk & 63, n0 = half * 32;
    int tid = threadIdx.x;

    precompute_coords<32>(off, b, h, n0, tid, s_wt, s_off);
    if (tid < 32) {
        int n = rowblk * 64 + n0 + tid;
        float lg = att_part[n] + att_part[16384 + n] + att_part[32768 + n] + att_part[49152 + n] + att_b[0];
        s_att[tid] = 1.f / (1.f + expf(-lg));
    }

    int lane = tid & 63, wv_id = tid >> 6;
    int wm0 = wv_id * 64;
    int l15 = lane & 15, kb = lane >> 4;

    f32x4 acc[4][2];
#pragma unroll
    for (int mt = 0; mt < 4; ++mt)
#pragma unroll
        for (int nt = 0; nt < 2; ++nt) acc[mt][nt] = (f32x4){0.f, 0.f, 0.f, 0.f};

    // fragment LDS indices (ushort units)
    int aidx[4], bidx[2];
#pragma unroll
    for (int mt = 0; mt < 4; ++mt) {
        int m = wm0 + mt * 16 + l15;
        aidx[mt] = m * 32 + ((kb ^ ((m >> 1) & 3)) << 3);
    }
#pragma unroll
    for (int nt = 0; nt < 2; ++nt) {
        int n = nt * 16 + l15;
        bidx[nt] = n * 32 + ((kb ^ ((n >> 1) & 3)) << 3);
    }

    const float* xbase = x + ((size_t)b * CT << 12);

    for (int kc = 0; kc < NSTEP; ++kc) {
        __syncthreads();
        // W stage: 64B/thread, lane-linear 16B units (coalesced global, conflict-free LDS)
        uint4 wreg[4];
#pragma unroll
        for (int i = 0; i < 4; ++i)
            wreg[i] = pw[kc * 1024 + i * 256 + tid];
        // col gather: 4 bilinear samples/thread
        float cv[4];
#pragma unroll
        for (int i = 0; i < 4; ++i) {
            int e = tid + i * 256;
            int kloc = e >> 5, n = e & 31;
            int k = kc * 32 + kloc;
            int c = k / 9, tap = k - c * 9;
            int2 of = s_off[tap * 32 + n];
            float4 wt = s_wt[tap * 32 + n];
            const float* xc = xbase + ((size_t)c << 12);
            cv[i] = wt.x * xc[of.x & 0xffff] + wt.y * xc[(of.x >> 16) & 0xffff]
                  + wt.z * xc[of.y & 0xffff] + wt.w * xc[(of.y >> 16) & 0xffff];
        }
#pragma unroll
        for (int i = 0; i < 4; ++i)
            ((uint4*)Wl)[i * 256 + tid] = wreg[i];
#pragma unroll
        for (int i = 0; i < 4; ++i) {
            int e = tid + i * 256;
            int kloc = e >> 5, n = e & 31;
            Cl[n * 32 + (((kloc >> 3) ^ ((n >> 1) & 3)) << 3) + (kloc & 7)] = (unsigned short)f2b(cv[i]);
        }
        __syncthreads();

        bf16x8 bfr[2];
#pragma unroll
        for (int nt = 0; nt < 2; ++nt) bfr[nt] = *(const bf16x8*)&Cl[bidx[nt]];
#pragma unroll
        for (int mt = 0; mt < 4; ++mt) {
            bf16x8 afr = *(const bf16x8*)&Wl[aidx[mt]];
#pragma unroll
            for (int nt = 0; nt < 2; ++nt)
                acc[mt][nt] = __builtin_amdgcn_mfma_f32_16x16x32_bf16(afr, bfr[nt], acc[mt][nt], 0, 0, 0);
        }
    }

    // epilogue: D layout col = lane&15 (n), row = (lane>>4)*4 + reg (m)
    float av[2];
    av[0] = s_att[l15];
    av[1] = s_att[16 + l15];
#pragma unroll
    for (int mt = 0; mt < 4; ++mt)
#pragma unroll
        for (int nt = 0; nt < 2; ++nt)
#pragma unroll
            for (int r = 0; r < 4; ++r) {
                int m = wm0 + mt * 16 + kb * 4 + r;
                int wc = n0 + nt * 16 + l15;
                outp[(((size_t)(b * CT + m)) << 12) + h * 64 + wc] = acc[mt][nt][r] * av[nt];
            }
}

// GroupNorm stats. One block per (b,g) group = 32768 contiguous floats.
__global__ __launch_bounds__(256) void k_gnstats(const float* __restrict__ outp, float* __restrict__ stats)
{
    int bg = blockIdx.x;
    const float4* p4 = (const float4*)(outp + (size_t)bg * 32768);
    int tid = threadIdx.x;
    float s = 0.f, s2 = 0.f;
    for (int i = tid; i < 8192; i += 256) {
        float4 v = p4[i];
        s += (v.x + v.y) + (v.z + v.w);
        s2 += v.x * v.x + v.y * v.y + v.z * v.z + v.w * v.w;
    }
#pragma unroll
    for (int d = 32; d; d >>= 1) {
        s += __shfl_down(s, d);
        s2 += __shfl_down(s2, d);
    }
    __shared__ float rs[4], rs2[4];
    if ((tid & 63) == 0) { rs[tid >> 6] = s; rs2[tid >> 6] = s2; }
    __syncthreads();
    if (tid == 0) {
        float S = rs[0] + rs[1] + rs[2] + rs[3];
        float S2 = rs2[0] + rs2[1] + rs2[2] + rs2[3];
        float mean = S * (1.f / 32768.f);
        float var = S2 * (1.f / 32768.f) - mean * mean;
        stats[bg * 2] = mean;
        stats[bg * 2 + 1] = rsqrtf(var + 1e-5f);
    }
}

// Normalize + affine + ReLU, in place, float4 per thread.
__global__ __launch_bounds__(256) void k_gnorm(float* __restrict__ outp, const float* __restrict__ stats,
                                               const float* __restrict__ gamma, const float* __restrict__ beta)
{
    int idx = blockIdx.x * 256 + threadIdx.x;      // [0, 1048576)
    size_t e = (size_t)idx * 4;
    int c = (int)((e >> 12) & 255);
    int bg = (int)(e >> 15);
    float mean = stats[bg * 2], rstd = stats[bg * 2 + 1];
    float ga = gamma[c], be = beta[c];
    float4 v = ((const float4*)outp)[idx];
    float4 r;
    r.x = fmaxf((v.x - mean) * rstd * ga + be, 0.f);
    r.y = fmaxf((v.y - mean) * rstd * ga + be, 0.f);
    r.z = fmaxf((v.z - mean) * rstd * ga + be, 0.f);
    r.w = fmaxf((v.w - mean) * rstd * ga + be, 0.f);
    ((float4*)outp)[idx] = r;
}

extern "C" void kernel_launch(void* const* d_in, const int* in_sizes, int n_in,
                              void* d_out, int out_size, void* d_ws, size_t ws_size,
                              hipStream_t stream)
{
    const float* x = (const float*)d_in[0];
    const float* off = (const float*)d_in[1];
    const float* wgt = (const float*)d_in[2];
    const float* attw = (const float*)d_in[3];
    const float* attb = (const float*)d_in[4];
    const float* gamma = (const float*)d_in[5];
    const float* beta = (const float*)d_in[6];
    float* outp = (float*)d_out;

    float* ws_f = (float*)d_ws;
    float* att_part = ws_f;                 // 4 * 16384 floats
    float* stats = ws_f + 65536;            // 256 floats
    uint4* pw = (uint4*)(ws_f + 65792);     // 73728 uint4 = 1.125 MB (16B-aligned)

    k_prep<<<dim3(288), dim3(256), 0, stream>>>(wgt, pw);
    k_att<<<dim3(1024), dim3(256), 0, stream>>>(x, off, attw, att_part);
    k_conv<<<dim3(512), dim3(256), 0, stream>>>(x, off, pw, att_part, attb, outp);
    k_gnstats<<<dim3(128), dim3(256), 0, stream>>>(outp, stats);
    k_gnorm<<<dim3(4096), dim3(256), 0, stream>>>(outp, stats, gamma, beta);
}

// Round 5
// 271.319 us; speedup vs baseline: 2.4314x; 1.3036x over previous
//
#include <hip/hip_runtime.h>

#define CT 256
#define KDIM 2304    // 256 channels * 9 taps
#define NSTEP 72     // 2304 / 32

typedef unsigned short u16;
typedef __attribute__((ext_vector_type(8))) short bf16x8;
typedef __attribute__((ext_vector_type(4))) float f32x4;

// f32 -> bf16 bits, round-to-nearest-even (finite inputs only)
__device__ __forceinline__ unsigned f2b(float f) {
    unsigned u = __float_as_uint(f);
    u += 0x7fffu + ((u >> 16) & 1u);
    return u >> 16;
}
__device__ __forceinline__ float us2f(u16 v) { return __uint_as_float(((unsigned)v) << 16); }

// Bilinear coords + corner weights for the 64 positions of row (b,h).
// Zero-pad validity folded into weights; indices clamped to [0,63].
__device__ __forceinline__ void precompute_coords(const float* __restrict__ off, int b, int h,
                                                  int tid, float4* s_wt, int2* s_off)
{
    for (int e = tid; e < 576; e += 256) {
        int kk = e >> 6, w = e & 63;
        int ky = kk / 3, kx = kk - ky * 3;
        float dy = off[((size_t)(b * 18 + 2 * kk) * 64 + h) * 64 + w];
        float dx = off[((size_t)(b * 18 + 2 * kk + 1) * 64 + h) * 64 + w];
        float py = (float)(h + ky - 1) + dy;
        float px = (float)(w + kx - 1) + dx;
        float y0f = floorf(py), x0f = floorf(px);
        int y0 = (int)y0f, x0 = (int)x0f;
        float fy = py - y0f, fx = px - x0f;
        float vy0 = (y0 >= 0 && y0 < 64) ? 1.f : 0.f;
        float vy1 = (y0 >= -1 && y0 < 63) ? 1.f : 0.f;
        float vx0 = (x0 >= 0 && x0 < 64) ? 1.f : 0.f;
        float vx1 = (x0 >= -1 && x0 < 63) ? 1.f : 0.f;
        float4 wt;
        wt.x = (1.f - fy) * (1.f - fx) * vy0 * vx0;
        wt.y = (1.f - fy) * fx * vy0 * vx1;
        wt.z = fy * (1.f - fx) * vy1 * vx0;
        wt.w = fy * fx * vy1 * vx1;
        int yc0 = min(max(y0, 0), 63), yc1 = min(max(y0 + 1, 0), 63);
        int xc0 = min(max(x0, 0), 63), xc1 = min(max(x0 + 1, 0), 63);
        s_wt[kk * 64 + w] = wt;
        s_off[kk * 64 + w] = make_int2((yc0 * 64 + xc0) | ((yc0 * 64 + xc1) << 16),
                                       (yc1 * 64 + xc0) | ((yc1 * 64 + xc1) << 16));
    }
}

// Repack weight f32[256][2304] -> bf16 packed [kc][m][4 x 16B units], k-block XOR-swizzled.
__global__ __launch_bounds__(256) void k_prep(const float* __restrict__ wgt, uint4* __restrict__ pw)
{
    int u = blockIdx.x * 256 + threadIdx.x;        // [0, 73728)
    int kc = u >> 10, r = u & 1023;
    int m = r >> 2, j = r & 3;
    int jj = j ^ ((m >> 1) & 3);
    const float* src = wgt + (size_t)m * KDIM + kc * 32 + jj * 8;
    float4 a = *(const float4*)src;
    float4 c = *(const float4*)(src + 4);
    uint4 o;
    o.x = f2b(a.x) | (f2b(a.y) << 16);
    o.y = f2b(a.z) | (f2b(a.w) << 16);
    o.z = f2b(c.x) | (f2b(c.y) << 16);
    o.w = f2b(c.z) | (f2b(c.w) << 16);
    pw[u] = o;
}

// Deformable unfold via LDS-staged x + attention partials.
// Grid (256 rowblk, 16 cblk). Stages x[c0..c0+15][h-7..h+7] as bf16 in LDS, gathers all
// 16ch x 9tap x 64n samples from LDS (rare out-of-window -> global fallback),
// writes col bf16 [n][k] (coalesced via LDS transpose) + per-cblk attention partials.
__global__ __launch_bounds__(256) void k_unfold(const float* __restrict__ x, const float* __restrict__ off,
                                                const float* __restrict__ att_w,
                                                u16* __restrict__ col, float* __restrict__ att_part)
{
    __shared__ float4 s_wt[576];
    __shared__ int2 s_off[576];
    __shared__ u16 Xs[16 * 964];       // 16 channel planes, <=15 rows x 64, +4 pad shorts
    __shared__ float s_part[4][64];

    int rowblk = blockIdx.x, cblk = blockIdx.y;
    int b = rowblk >> 6, h = rowblk & 63;
    int c0 = cblk * 16;
    int tid = threadIdx.x;

    precompute_coords(off, b, h, tid, s_wt, s_off);

    int r0 = max(0, h - 7), r1 = min(63, h + 7);
    int nrows = r1 - r0 + 1;
    int nw = nrows * 64;
    int nr4 = nrows * 16;              // float4 units per plane (<=240)
    // stage x -> bf16 LDS
    for (int c = 0; c < 16; ++c) {
        if (tid < nr4) {
            const float* xp = x + (((size_t)(b * CT + c0 + c)) << 12) + r0 * 64 + tid * 4;
            float4 v = *(const float4*)xp;
            uint2 p;
            p.x = f2b(v.x) | (f2b(v.y) << 16);
            p.y = f2b(v.z) | (f2b(v.w) << 16);
            *(uint2*)&Xs[c * 964 + tid * 4] = p;
        }
    }
    __syncthreads();

    int n = tid & 63, csub = tid >> 6;
    int rbase = r0 * 64;
    const float* xg = x + (((size_t)(b * CT + c0 + csub * 4)) << 12);
    float vals[36];
    float maxv[4];
#pragma unroll
    for (int cs = 0; cs < 4; ++cs) maxv[cs] = -1e30f;

#pragma unroll
    for (int tap = 0; tap < 9; ++tap) {
        float4 wt = s_wt[tap * 64 + n];
        int2 of = s_off[tap * 64 + n];
        int i00 = of.x & 0xffff, i01 = (of.x >> 16) & 0xffff;
        int i10 = of.y & 0xffff, i11 = (of.y >> 16) & 0xffff;
        int r00 = i00 - rbase, r01 = i01 - rbase;
        int r10 = i10 - rbase, r11 = i11 - rbase;
#pragma unroll
        for (int cs = 0; cs < 4; ++cs) {
            int pl = (csub * 4 + cs) * 964;
            const float* xc = xg + ((size_t)cs << 12);
            float c00 = ((unsigned)r00 < (unsigned)nw) ? us2f(Xs[pl + r00]) : xc[i00];
            float c01 = ((unsigned)r01 < (unsigned)nw) ? us2f(Xs[pl + r01]) : xc[i01];
            float c10 = ((unsigned)r10 < (unsigned)nw) ? us2f(Xs[pl + r10]) : xc[i10];
            float c11 = ((unsigned)r11 < (unsigned)nw) ? us2f(Xs[pl + r11]) : xc[i11];
            float v = wt.x * c00 + wt.y * c01 + wt.z * c10 + wt.w * c11;
            vals[cs * 9 + tap] = v;
            maxv[cs] = fmaxf(maxv[cs], v);
        }
    }
    float acc = 0.f;
#pragma unroll
    for (int cs = 0; cs < 4; ++cs) acc += att_w[c0 + csub * 4 + cs] * maxv[cs];
    s_part[csub][n] = acc;
    __syncthreads();   // all Xs gather-reads done; safe to reuse Xs as col-stage

    // col-stage: row n = 144 data shorts (pad to 152), thread writes its 36 shorts
#pragma unroll
    for (int t = 0; t < 9; ++t) {
        uint2 p;
        p.x = f2b(vals[4 * t]) | (f2b(vals[4 * t + 1]) << 16);
        p.y = f2b(vals[4 * t + 2]) | (f2b(vals[4 * t + 3]) << 16);
        *(uint2*)&Xs[n * 152 + csub * 36 + t * 4] = p;
    }
    if (csub == 0)
        att_part[cblk * 16384 + rowblk * 64 + n] =
            s_part[0][n] + s_part[1][n] + s_part[2][n] + s_part[3][n];
    __syncthreads();

    // coalesced writeout: 64 rows x 18 uint4
    for (int u = tid; u < 1152; u += 256) {
        int rn = u / 18, j = u - rn * 18;
        uint4 v = *(const uint4*)&Xs[rn * 152 + j * 8];
        *(uint4*)(col + ((size_t)(rowblk * 64 + rn)) * KDIM + cblk * 144 + j * 8) = v;
    }
}

// Sum 16 partials + bias -> sigmoid
__global__ __launch_bounds__(256) void k_logit(const float* __restrict__ att_part,
                                               const float* __restrict__ att_b, float* __restrict__ att)
{
    int p = blockIdx.x * 256 + threadIdx.x;
    float s = att_b[0];
#pragma unroll
    for (int g = 0; g < 16; ++g) s += att_part[g * 16384 + p];
    att[p] = 1.f / (1.f + expf(-s));
}

// bf16 MFMA GEMM: out[m][p] = att[p] * sum_k W[m][k] col[p][k]. M=256, N=16384, K=2304.
// Grid 256 (n-tiles of 64), 512 threads = 8 waves; wave = 64m x 32n = 4x2 MFMA frags.
__global__ __launch_bounds__(512) void k_gemm(const uint4* __restrict__ pw, const u16* __restrict__ col,
                                              const float* __restrict__ att, float* __restrict__ outp)
{
    __shared__ u16 As[8192];           // 16 KB A-tile (256m x 32k bf16, swizzled)
    int nblk = blockIdx.x;
    int tid = threadIdx.x;
    int lane = tid & 63, w = tid >> 6;
    int l15 = lane & 15, kb = lane >> 4;
    int wm = (w & 3) * 64, wn = (w >> 2) * 32;

    f32x4 acc[4][2];
#pragma unroll
    for (int mt = 0; mt < 4; ++mt)
#pragma unroll
        for (int nt = 0; nt < 2; ++nt) acc[mt][nt] = (f32x4){0.f, 0.f, 0.f, 0.f};

    int aidx[4];
#pragma unroll
    for (int mt = 0; mt < 4; ++mt) {
        int m = wm + mt * 16 + l15;
        aidx[mt] = (m * 4 + (kb ^ ((m >> 1) & 3))) * 8;
    }
    size_t bbase[2];
#pragma unroll
    for (int nt = 0; nt < 2; ++nt) {
        int gn = nblk * 64 + wn + nt * 16 + l15;
        bbase[nt] = (size_t)gn * KDIM + kb * 8;
    }

    for (int kc = 0; kc < NSTEP; ++kc) {
        __syncthreads();
        uint4 a0 = pw[kc * 1024 + tid];
        uint4 a1 = pw[kc * 1024 + 512 + tid];
        bf16x8 bfr[2];
#pragma unroll
        for (int nt = 0; nt < 2; ++nt)
            bfr[nt] = *(const bf16x8*)(col + bbase[nt] + kc * 32);
        ((uint4*)As)[tid] = a0;
        ((uint4*)As)[512 + tid] = a1;
        __syncthreads();
#pragma unroll
        for (int mt = 0; mt < 4; ++mt) {
            bf16x8 afr = *(const bf16x8*)&As[aidx[mt]];
#pragma unroll
            for (int nt = 0; nt < 2; ++nt)
                acc[mt][nt] = __builtin_amdgcn_mfma_f32_16x16x32_bf16(afr, bfr[nt], acc[mt][nt], 0, 0, 0);
        }
    }

    float av[2];
#pragma unroll
    for (int nt = 0; nt < 2; ++nt) av[nt] = att[nblk * 64 + wn + nt * 16 + l15];
#pragma unroll
    for (int mt = 0; mt < 4; ++mt)
#pragma unroll
        for (int nt = 0; nt < 2; ++nt)
#pragma unroll
            for (int r = 0; r < 4; ++r) {
                int m = wm + mt * 16 + kb * 4 + r;
                int p = nblk * 64 + wn + nt * 16 + l15;
                int b = p >> 12;
                outp[(((size_t)(b * CT + m)) << 12) + (p & 4095)] = acc[mt][nt][r] * av[nt];
            }
}

// GroupNorm stats. One block per (b,g) group = 32768 contiguous floats.
__global__ __launch_bounds__(256) void k_gnstats(const float* __restrict__ outp, float* __restrict__ stats)
{
    int bg = blockIdx.x;
    const float4* p4 = (const float4*)(outp + (size_t)bg * 32768);
    int tid = threadIdx.x;
    float s = 0.f, s2 = 0.f;
    for (int i = tid; i < 8192; i += 256) {
        float4 v = p4[i];
        s += (v.x + v.y) + (v.z + v.w);
        s2 += v.x * v.x + v.y * v.y + v.z * v.z + v.w * v.w;
    }
#pragma unroll
    for (int d = 32; d; d >>= 1) {
        s += __shfl_down(s, d);
        s2 += __shfl_down(s2, d);
    }
    __shared__ float rs[4], rs2[4];
    if ((tid & 63) == 0) { rs[tid >> 6] = s; rs2[tid >> 6] = s2; }
    __syncthreads();
    if (tid == 0) {
        float S = rs[0] + rs[1] + rs[2] + rs[3];
        float S2 = rs2[0] + rs2[1] + rs2[2] + rs2[3];
        float mean = S * (1.f / 32768.f);
        float var = S2 * (1.f / 32768.f) - mean * mean;
        stats[bg * 2] = mean;
        stats[bg * 2 + 1] = rsqrtf(var + 1e-5f);
    }
}

// Normalize + affine + ReLU, in place, float4 per thread.
__global__ __launch_bounds__(256) void k_gnorm(float* __restrict__ outp, const float* __restrict__ stats,
                                               const float* __restrict__ gamma, const float* __restrict__ beta)
{
    int idx = blockIdx.x * 256 + threadIdx.x;      // [0, 1048576)
    size_t e = (size_t)idx * 4;
    int c = (int)((e >> 12) & 255);
    int bg = (int)(e >> 15);
    float mean = stats[bg * 2], rstd = stats[bg * 2 + 1];
    float ga = gamma[c], be = beta[c];
    float4 v = ((const float4*)outp)[idx];
    float4 r;
    r.x = fmaxf((v.x - mean) * rstd * ga + be, 0.f);
    r.y = fmaxf((v.y - mean) * rstd * ga + be, 0.f);
    r.z = fmaxf((v.z - mean) * rstd * ga + be, 0.f);
    r.w = fmaxf((v.w - mean) * rstd * ga + be, 0.f);
    ((float4*)outp)[idx] = r;
}

extern "C" void kernel_launch(void* const* d_in, const int* in_sizes, int n_in,
                              void* d_out, int out_size, void* d_ws, size_t ws_size,
                              hipStream_t stream)
{
    const float* x = (const float*)d_in[0];
    const float* off = (const float*)d_in[1];
    const float* wgt = (const float*)d_in[2];
    const float* attw = (const float*)d_in[3];
    const float* attb = (const float*)d_in[4];
    const float* gamma = (const float*)d_in[5];
    const float* beta = (const float*)d_in[6];
    float* outp = (float*)d_out;

    char* ws = (char*)d_ws;
    u16* col = (u16*)ws;                                    // 16384*2304 bf16 = 75.5 MB
    uint4* pw = (uint4*)(ws + (size_t)16384 * KDIM * 2);    // 1.18 MB
    float* att_part = (float*)(ws + 76677120);              // 16*16384 f32 = 1 MB
    float* att = (float*)(ws + 77725696);                   // 64 KB
    float* stats = (float*)(ws + 77791232);                 // 2 KB

    k_prep<<<dim3(288), dim3(256), 0, stream>>>(wgt, pw);
    k_unfold<<<dim3(256, 16), dim3(256), 0, stream>>>(x, off, attw, col, att_part);
    k_logit<<<dim3(64), dim3(256), 0, stream>>>(att_part, attb, att);
    k_gemm<<<dim3(256), dim3(512), 0, stream>>>(pw, col, att, outp);
    k_gnstats<<<dim3(128), dim3(256), 0, stream>>>(outp, stats);
    k_gnorm<<<dim3(4096), dim3(256), 0, stream>>>(outp, stats, gamma, beta);
}

// Round 7
// 174.788 us; speedup vs baseline: 3.7742x; 1.5523x over previous
//
#include <hip/hip_runtime.h>

#define CT 256
#define KDIM 2304
#define ROUNDS 8
#define COLP 296         // padded col row stride in shorts (592B: 16B-aligned, 2-way banks)

typedef unsigned short u16;
typedef __attribute__((ext_vector_type(8))) short bf16x8;
typedef __attribute__((ext_vector_type(4))) float f32x4;

__device__ __forceinline__ unsigned f2b(float f) {       // f32 -> bf16 bits, RTE
    unsigned u = __float_as_uint(f);
    u += 0x7fffu + ((u >> 16) & 1u);
    return u >> 16;
}
__device__ __forceinline__ float us2f(u16 v) { return __uint_as_float(((unsigned)v) << 16); }
__device__ __forceinline__ float lo_bf(unsigned u) { return __uint_as_float(u << 16); }
__device__ __forceinline__ float hi_bf(unsigned u) { return __uint_as_float(u & 0xffff0000u); }

// x f32 [b][c][pos] -> xi bf16 interleaved-8: uint4 index u = (b*32+cg)*4096 + pos, holds ch cg*8..+8
__global__ __launch_bounds__(256) void k_xprep(const float* __restrict__ x, uint4* __restrict__ xi)
{
    int u = blockIdx.x * 256 + threadIdx.x;        // [0, 524288)
    int bcg = u >> 12, p = u & 4095;
    const float* xp = x + (((size_t)bcg) << 15) + p;   // channel base = bcg*8
    unsigned r[4];
#pragma unroll
    for (int i = 0; i < 4; ++i) {
        float a = xp[(size_t)(2 * i) << 12];
        float c = xp[(size_t)(2 * i + 1) << 12];
        r[i] = f2b(a) | (f2b(c) << 16);
    }
    uint4 o; o.x = r[0]; o.y = r[1]; o.z = r[2]; o.w = r[3];
    xi[u] = o;
}

// W f32 [m][k=c*9+tap] -> pw bf16: unit u=(kc,m,j) holds k' = kc*32+j*8+e, where
// k' = round*288 + tap*32 + cl  (round=kc/9, tap=kc%9, cl=j*8+e, c=round*32+cl)
__global__ __launch_bounds__(256) void k_wprep(const float* __restrict__ wgt, uint4* __restrict__ pw)
{
    int u = blockIdx.x * 256 + threadIdx.x;        // [0, 73728)
    int kc = u >> 10, rm = u & 1023;
    int m = rm >> 2, j = rm & 3;
    int round = kc / 9, tap = kc - round * 9;
    const float* src = wgt + (size_t)m * KDIM + tap;
    int c0 = round * 32 + j * 8;
    unsigned q[4];
#pragma unroll
    for (int i = 0; i < 4; ++i) {
        float a = src[(size_t)(c0 + 2 * i) * 9];
        float c = src[(size_t)(c0 + 2 * i + 1) * 9];
        q[i] = f2b(a) | (f2b(c) << 16);
    }
    uint4 o; o.x = q[0]; o.y = q[1]; o.z = q[2]; o.w = q[3];
    pw[u] = o;
}

// Fused: deformable unfold (LDS gather) + attention + MFMA GEMM + GN partials.
// 256 blocks (one per (b,h) row), 512 threads = 8 waves; wave w = rows [w*32, w*32+32) x all 64 n.
__global__ __launch_bounds__(512, 2) void k_main(const uint4* __restrict__ xi, const float* __restrict__ off,
                                                 const uint4* __restrict__ pw, const float* __restrict__ att_w,
                                                 const float* __restrict__ att_b,
                                                 float* __restrict__ outp, float* __restrict__ gnpart)
{
    __shared__ float4 s_wt[576];       // bilinear corner weights (f32)
    __shared__ int2 s_off[576];        // 4 corner positions packed u16
    __shared__ u16 Xs[7680];           // one superplane: 15 rows x 64 pos x 8 ch
    __shared__ u16 col[64 * COLP];     // 64 n x 288 k (padded)
    __shared__ float s_att[8][64];

    int rowblk = blockIdx.x;
    int b = rowblk >> 6, h = rowblk & 63;
    int tid = threadIdx.x;
    int lane = tid & 63, w = tid >> 6;
    int n = tid & 63, g = tid >> 6;
    int l15 = lane & 15, kb = lane >> 4;
    int wm = w * 32;

    // bilinear coords for this row (validity folded into weights, indices clamped)
    for (int e = tid; e < 576; e += 512) {
        int kk = e >> 6, ww_ = e & 63;
        int ky = kk / 3, kx = kk - ky * 3;
        float dy = off[((size_t)(b * 18 + 2 * kk) * 64 + h) * 64 + ww_];
        float dx = off[((size_t)(b * 18 + 2 * kk + 1) * 64 + h) * 64 + ww_];
        float py = (float)(h + ky - 1) + dy;
        float px = (float)(ww_ + kx - 1) + dx;
        float y0f = floorf(py), x0f = floorf(px);
        int y0 = (int)y0f, x0 = (int)x0f;
        float fy = py - y0f, fx = px - x0f;
        float vy0 = (y0 >= 0 && y0 < 64) ? 1.f : 0.f;
        float vy1 = (y0 >= -1 && y0 < 63) ? 1.f : 0.f;
        float vx0 = (x0 >= 0 && x0 < 64) ? 1.f : 0.f;
        float vx1 = (x0 >= -1 && x0 < 63) ? 1.f : 0.f;
        float4 wt;
        wt.x = (1.f - fy) * (1.f - fx) * vy0 * vx0;
        wt.y = (1.f - fy) * fx * vy0 * vx1;
        wt.z = fy * (1.f - fx) * vy1 * vx0;
        wt.w = fy * fx * vy1 * vx1;
        int yc0 = min(max(y0, 0), 63), yc1 = min(max(y0 + 1, 0), 63);
        int xc0 = min(max(x0, 0), 63), xc1 = min(max(x0 + 1, 0), 63);
        s_wt[e] = wt;
        s_off[e] = make_int2((yc0 * 64 + xc0) | ((yc0 * 64 + xc1) << 16),
                             (yc1 * 64 + xc0) | ((yc1 * 64 + xc1) << 16));
    }

    int r0 = max(0, h - 7), r1 = min(63, h + 7);
    int nrows = r1 - r0 + 1, nw = nrows * 64, rbase = r0 * 64;

    float att_acc = 0.f;
    f32x4 acc[2][4];
#pragma unroll
    for (int mt = 0; mt < 2; ++mt)
#pragma unroll
        for (int nt = 0; nt < 4; ++nt) acc[mt][nt] = (f32x4){0.f, 0.f, 0.f, 0.f};

    for (int round = 0; round < ROUNDS; ++round) {
        for (int sp = 0; sp < 4; ++sp) {
            int cg = round * 4 + sp;
            size_t xibase = (size_t)(b * 32 + cg) << 12;
            __syncthreads();           // Xs free (prev gather done); sp==0: col free (prev MFMA done)
            for (int u2 = tid; u2 < nrows * 64; u2 += 512)
                ((uint4*)Xs)[u2] = xi[xibase + rbase + u2];
            __syncthreads();           // Xs ready
            for (int it = tid; it < 576; it += 512) {
                int tap = it >> 6, nn = it & 63;
                float4 wt = s_wt[it];
                int2 of = s_off[it];
                float wx = wt.x, wy = wt.y, wz = wt.z, ww2 = wt.w;
                int P00 = of.x & 0xffff, P01 = (of.x >> 16) & 0xffff;
                int P10 = of.y & 0xffff, P11 = (of.y >> 16) & 0xffff;
                uint4 c00, c01, c10, c11;
                int Q;
                Q = P00 - rbase;
                if ((unsigned)Q < (unsigned)nw) c00 = *(const uint4*)&Xs[Q * 8]; else c00 = xi[xibase + P00];
                Q = P01 - rbase;
                if ((unsigned)Q < (unsigned)nw) c01 = *(const uint4*)&Xs[Q * 8]; else c01 = xi[xibase + P01];
                Q = P10 - rbase;
                if ((unsigned)Q < (unsigned)nw) c10 = *(const uint4*)&Xs[Q * 8]; else c10 = xi[xibase + P10];
                Q = P11 - rbase;
                if ((unsigned)Q < (unsigned)nw) c11 = *(const uint4*)&Xs[Q * 8]; else c11 = xi[xibase + P11];
                const unsigned* a00 = (const unsigned*)&c00;
                const unsigned* a01 = (const unsigned*)&c01;
                const unsigned* a10 = (const unsigned*)&c10;
                const unsigned* a11 = (const unsigned*)&c11;
                unsigned o[4];
#pragma unroll
                for (int q = 0; q < 4; ++q) {
                    float v0 = wx * lo_bf(a00[q]) + wy * lo_bf(a01[q]) + wz * lo_bf(a10[q]) + ww2 * lo_bf(a11[q]);
                    float v1 = wx * hi_bf(a00[q]) + wy * hi_bf(a01[q]) + wz * hi_bf(a10[q]) + ww2 * hi_bf(a11[q]);
                    o[q] = f2b(v0) | (f2b(v1) << 16);
                }
                uint4 ov; ov.x = o[0]; ov.y = o[1]; ov.z = o[2]; ov.w = o[3];
                *(uint4*)&col[nn * COLP + tap * 32 + sp * 8] = ov;
            }
            __syncthreads();           // col[sp] ready
            {   // tap-max + attention partial (max over bf16 == bf16 of max: RTE monotone)
                int base = n * COLP + sp * 8 + g;
                float mv = us2f(col[base]);
#pragma unroll
                for (int t = 1; t < 9; ++t) mv = fmaxf(mv, us2f(col[base + t * 32]));
                att_acc += att_w[round * 32 + sp * 8 + g] * mv;
            }
        }
        __syncthreads();               // full 288-k col ready; MFMA phase: no internal barriers
#pragma unroll
        for (int ts = 0; ts < 9; ++ts) {
            int kc = round * 9 + ts;
            bf16x8 bf[4];
#pragma unroll
            for (int nt = 0; nt < 4; ++nt)
                bf[nt] = *(const bf16x8*)&col[(nt * 16 + l15) * COLP + ts * 32 + kb * 8];
#pragma unroll
            for (int mt = 0; mt < 2; ++mt) {
                uint4 a = pw[(size_t)kc * 1024 + (wm + mt * 16 + l15) * 4 + kb];
                bf16x8 af = __builtin_bit_cast(bf16x8, a);
#pragma unroll
                for (int nt = 0; nt < 4; ++nt)
                    acc[mt][nt] = __builtin_amdgcn_mfma_f32_16x16x32_bf16(af, bf[nt], acc[mt][nt], 0, 0, 0);
            }
        }
    }

    // attention logits
    s_att[g][n] = att_acc;
    __syncthreads();
    if (tid < 64) {
        float s = att_b[0];
#pragma unroll
        for (int q = 0; q < 8; ++q) s += s_att[q][tid];
        s_att[0][tid] = 1.f / (1.f + expf(-s));
    }
    __syncthreads();

    float attn[4];
#pragma unroll
    for (int nt = 0; nt < 4; ++nt) attn[nt] = s_att[0][nt * 16 + l15];

    // epilogue: scale by att, write out, GN partial sums (group = m>>3)
#pragma unroll
    for (int mt = 0; mt < 2; ++mt) {
        float s1 = 0.f, s2 = 0.f;
#pragma unroll
        for (int nt = 0; nt < 4; ++nt)
#pragma unroll
            for (int r = 0; r < 4; ++r) {
                float v = acc[mt][nt][r] * attn[nt];
                int m = wm + mt * 16 + kb * 4 + r;
                outp[(((size_t)(b * CT + m)) << 12) + h * 64 + nt * 16 + l15] = v;
                s1 += v; s2 += v * v;
            }
#pragma unroll
        for (int d = 1; d <= 16; d <<= 1) {
            s1 += __shfl_xor(s1, d);
            s2 += __shfl_xor(s2, d);
        }
        if ((lane & 31) == 0) {        // lanes 0 (kb 0/1 half) and 32 (kb 2/3 half)
            int gidx = w * 4 + mt * 2 + (kb >> 1);
            gnpart[rowblk * 64 + gidx * 2] = s1;
            gnpart[rowblk * 64 + gidx * 2 + 1] = s2;
        }
    }
}

// Reduce 64 row-partials per (b,g) -> mean/rstd
__global__ __launch_bounds__(128) void k_gnfinal(const float* __restrict__ gnpart, float* __restrict__ stats)
{
    int p = threadIdx.x;               // [0,128): b = p>>5, g = p&31
    int bb = p >> 5, gg = p & 31;
    float S1 = 0.f, S2 = 0.f;
    for (int hh = 0; hh < 64; ++hh) {
        S1 += gnpart[(bb * 64 + hh) * 64 + gg * 2];
        S2 += gnpart[(bb * 64 + hh) * 64 + gg * 2 + 1];
    }
    float mean = S1 * (1.f / 32768.f);
    float var = S2 * (1.f / 32768.f) - mean * mean;
    stats[p * 2] = mean;
    stats[p * 2 + 1] = rsqrtf(var + 1e-5f);
}

// Normalize + affine + ReLU, in place, float4 per thread.
__global__ __launch_bounds__(256) void k_gnorm(float* __restrict__ outp, const float* __restrict__ stats,
                                               const float* __restrict__ gamma, const float* __restrict__ beta)
{
    int idx = blockIdx.x * 256 + threadIdx.x;      // [0, 1048576)
    size_t e = (size_t)idx * 4;
    int c = (int)((e >> 12) & 255);
    int bg = (int)(e >> 15);
    float mean = stats[bg * 2], rstd = stats[bg * 2 + 1];
    float ga = gamma[c], be = beta[c];
    float4 v = ((const float4*)outp)[idx];
    float4 r;
    r.x = fmaxf((v.x - mean) * rstd * ga + be, 0.f);
    r.y = fmaxf((v.y - mean) * rstd * ga + be, 0.f);
    r.z = fmaxf((v.z - mean) * rstd * ga + be, 0.f);
    r.w = fmaxf((v.w - mean) * rstd * ga + be, 0.f);
    ((float4*)outp)[idx] = r;
}

extern "C" void kernel_launch(void* const* d_in, const int* in_sizes, int n_in,
                              void* d_out, int out_size, void* d_ws, size_t ws_size,
                              hipStream_t stream)
{
    const float* x = (const float*)d_in[0];
    const float* off = (const float*)d_in[1];
    const float* wgt = (const float*)d_in[2];
    const float* attw = (const float*)d_in[3];
    const float* attb = (const float*)d_in[4];
    const float* gamma = (const float*)d_in[5];
    const float* beta = (const float*)d_in[6];
    float* outp = (float*)d_out;

    char* ws = (char*)d_ws;
    uint4* xi = (uint4*)ws;                          // 524288 uint4 = 8.39 MB
    uint4* pw = (uint4*)(ws + 8388608);              // 73728 uint4 = 1.18 MB
    float* gnpart = (float*)(ws + 9568256);          // 256*64 f32 = 64 KB
    float* stats = (float*)(ws + 9633792);           // 128*2 f32

    k_xprep<<<dim3(2048), dim3(256), 0, stream>>>(x, xi);
    k_wprep<<<dim3(288), dim3(256), 0, stream>>>(wgt, pw);
    k_main<<<dim3(256), dim3(512), 0, stream>>>(xi, off, pw, attw, attb, outp, gnpart);
    k_gnfinal<<<dim3(1), dim3(128), 0, stream>>>(gnpart, stats);
    k_gnorm<<<dim3(4096), dim3(256), 0, stream>>>(outp, stats, gamma, beta);
}

// Round 8
// 167.202 us; speedup vs baseline: 3.9455x; 1.0454x over previous
//
#include <hip/hip_runtime.h>

#define CT 256
#define KDIM 2304
#define ROUNDS 8
#define COLP 296         // padded col row stride in shorts

typedef unsigned short u16;
typedef __attribute__((ext_vector_type(8))) short bf16x8;
typedef __attribute__((ext_vector_type(4))) float f32x4;

__device__ __forceinline__ unsigned f2b(float f) {       // f32 -> bf16 bits, RTE
    unsigned u = __float_as_uint(f);
    u += 0x7fffu + ((u >> 16) & 1u);
    return u >> 16;
}
__device__ __forceinline__ float lo_bf(unsigned u) { return __uint_as_float(u << 16); }
__device__ __forceinline__ float hi_bf(unsigned u) { return __uint_as_float(u & 0xffff0000u); }

// Fused prep: blocks [0,2048) = x -> xi (bf16 interleaved-8); [2048,2336) = W -> pw.
// xi: uint4 u = (b*32+cg)*4096 + pos holds ch cg*8..cg*8+8 at pos.
// pw: unit u=(kc,m,j) holds k' = kc*32+j*8+e where k' = round*288 + tap*32 + cl,
//     round=kc/9, tap=kc%9, cl=j*8+e, src channel c = round*32+cl, src k = c*9+tap.
__global__ __launch_bounds__(256) void k_prep(const float* __restrict__ x, uint4* __restrict__ xi,
                                              const float* __restrict__ wgt, uint4* __restrict__ pw)
{
    if (blockIdx.x < 2048) {
        int u = blockIdx.x * 256 + threadIdx.x;        // [0, 524288)
        int bcg = u >> 12, p = u & 4095;
        const float* xp = x + (((size_t)bcg) << 15) + p;
        unsigned r[4];
#pragma unroll
        for (int i = 0; i < 4; ++i) {
            float a = xp[(size_t)(2 * i) << 12];
            float c = xp[(size_t)(2 * i + 1) << 12];
            r[i] = f2b(a) | (f2b(c) << 16);
        }
        uint4 o; o.x = r[0]; o.y = r[1]; o.z = r[2]; o.w = r[3];
        xi[u] = o;
    } else {
        int u = (blockIdx.x - 2048) * 256 + threadIdx.x;   // [0, 73728)
        int kc = u >> 10, rm = u & 1023;
        int m = rm >> 2, j = rm & 3;
        int round = kc / 9, tap = kc - round * 9;
        const float* src = wgt + (size_t)m * KDIM + tap;
        int c0 = round * 32 + j * 8;
        unsigned q[4];
#pragma unroll
        for (int i = 0; i < 4; ++i) {
            float a = src[(size_t)(c0 + 2 * i) * 9];
            float c = src[(size_t)(c0 + 2 * i + 1) * 9];
            q[i] = f2b(a) | (f2b(c) << 16);
        }
        uint4 o; o.x = q[0]; o.y = q[1]; o.z = q[2]; o.w = q[3];
        pw[u] = o;
    }
}

// Fused: deformable unfold (LDS gather) + attention + MFMA GEMM + GN partials.
// Grid 512: blockIdx.x = rowblk*2 + half; block = 32 positions x full M=256.
// 512 threads = 8 waves; wave w = m in [w*32, w*32+32) x all 32 n (2x2 MFMA frags).
__global__ __launch_bounds__(512, 2) void k_main(const uint4* __restrict__ xi, const float* __restrict__ off,
                                                 const uint4* __restrict__ pw, const float* __restrict__ att_w,
                                                 const float* __restrict__ att_b,
                                                 float* __restrict__ outp, float* __restrict__ gnpart)
{
    __shared__ float4 s_wt[288];       // bilinear corner weights (9 taps x 32 n)
    __shared__ int2 s_off[288];        // packed corner positions
    __shared__ u16 Xs[7680];           // superplane window: <=15 rows x 64 pos x 8 ch
    __shared__ u16 col[32 * COLP];     // 32 n x 288 k (padded)
    __shared__ float s_att[32];

    int rowblk = blockIdx.x >> 1, half = blockIdx.x & 1;
    int b = rowblk >> 6, h = rowblk & 63, n0 = half * 32;
    int tid = threadIdx.x;
    int lane = tid & 63, w = tid >> 6;
    int l15 = lane & 15, kb = lane >> 4;
    int wm = w * 32;

    // bilinear coords for this block's 32 positions
    for (int e = tid; e < 288; e += 512) {
        int kk = e >> 5, wl = e & 31;
        int ww_ = n0 + wl;
        int ky = kk / 3, kx = kk - ky * 3;
        float dy = off[((size_t)(b * 18 + 2 * kk) * 64 + h) * 64 + ww_];
        float dx = off[((size_t)(b * 18 + 2 * kk + 1) * 64 + h) * 64 + ww_];
        float py = (float)(h + ky - 1) + dy;
        float px = (float)(ww_ + kx - 1) + dx;
        float y0f = floorf(py), x0f = floorf(px);
        int y0 = (int)y0f, x0 = (int)x0f;
        float fy = py - y0f, fx = px - x0f;
        float vy0 = (y0 >= 0 && y0 < 64) ? 1.f : 0.f;
        float vy1 = (y0 >= -1 && y0 < 63) ? 1.f : 0.f;
        float vx0 = (x0 >= 0 && x0 < 64) ? 1.f : 0.f;
        float vx1 = (x0 >= -1 && x0 < 63) ? 1.f : 0.f;
        float4 wt;
        wt.x = (1.f - fy) * (1.f - fx) * vy0 * vx0;
        wt.y = (1.f - fy) * fx * vy0 * vx1;
        wt.z = fy * (1.f - fx) * vy1 * vx0;
        wt.w = fy * fx * vy1 * vx1;
        int yc0 = min(max(y0, 0), 63), yc1 = min(max(y0 + 1, 0), 63);
        int xc0 = min(max(x0, 0), 63), xc1 = min(max(x0 + 1, 0), 63);
        s_wt[e] = wt;
        s_off[e] = make_int2((yc0 * 64 + xc0) | ((yc0 * 64 + xc1) << 16),
                             (yc1 * 64 + xc0) | ((yc1 * 64 + xc1) << 16));
    }

    int r0 = max(0, h - 7), r1 = min(63, h + 7);
    int nrows = r1 - r0 + 1, nw = nrows * 64, rbase = r0 * 64;

    float att_acc = 0.f;
    f32x4 acc[2][2];
#pragma unroll
    for (int mt = 0; mt < 2; ++mt)
#pragma unroll
        for (int nt = 0; nt < 2; ++nt) acc[mt][nt] = (f32x4){0.f, 0.f, 0.f, 0.f};

    for (int round = 0; round < ROUNDS; ++round) {
        for (int sp = 0; sp < 4; ++sp) {
            int cg = round * 4 + sp;
            size_t xibase = (size_t)(b * 32 + cg) << 12;
            __syncthreads();           // Xs free / col slice free
            for (int u2 = tid; u2 < nrows * 64; u2 += 512)
                ((uint4*)Xs)[u2] = xi[xibase + rbase + u2];
            __syncthreads();           // Xs ready
            for (int it = tid; it < 288; it += 512) {
                int tap = it >> 5, nn = it & 31;
                float4 wt = s_wt[it];
                int2 of = s_off[it];
                int P00 = of.x & 0xffff, P01 = (of.x >> 16) & 0xffff;
                int P10 = of.y & 0xffff, P11 = (of.y >> 16) & 0xffff;
                uint4 c00, c01, c10, c11;
                int Q;
                Q = P00 - rbase;
                if ((unsigned)Q < (unsigned)nw) c00 = *(const uint4*)&Xs[Q * 8]; else c00 = xi[xibase + P00];
                Q = P01 - rbase;
                if ((unsigned)Q < (unsigned)nw) c01 = *(const uint4*)&Xs[Q * 8]; else c01 = xi[xibase + P01];
                Q = P10 - rbase;
                if ((unsigned)Q < (unsigned)nw) c10 = *(const uint4*)&Xs[Q * 8]; else c10 = xi[xibase + P10];
                Q = P11 - rbase;
                if ((unsigned)Q < (unsigned)nw) c11 = *(const uint4*)&Xs[Q * 8]; else c11 = xi[xibase + P11];
                const unsigned* a00 = (const unsigned*)&c00;
                const unsigned* a01 = (const unsigned*)&c01;
                const unsigned* a10 = (const unsigned*)&c10;
                const unsigned* a11 = (const unsigned*)&c11;
                unsigned o[4];
#pragma unroll
                for (int q = 0; q < 4; ++q) {
                    float v0 = wt.x * lo_bf(a00[q]) + wt.y * lo_bf(a01[q]) + wt.z * lo_bf(a10[q]) + wt.w * lo_bf(a11[q]);
                    float v1 = wt.x * hi_bf(a00[q]) + wt.y * hi_bf(a01[q]) + wt.z * hi_bf(a10[q]) + wt.w * hi_bf(a11[q]);
                    o[q] = f2b(v0) | (f2b(v1) << 16);
                }
                uint4 ov; ov.x = o[0]; ov.y = o[1]; ov.z = o[2]; ov.w = o[3];
                *(uint4*)&col[nn * COLP + tap * 32 + sp * 8] = ov;
            }
        }
        __syncthreads();               // full 288-k col slice ready

        // attention tap-max + dot: wave 0 only; lane = nn*2 + h2 (4 channels per lane, b64 reads)
        if (tid < 64) {
            int nn = tid >> 1, h2 = tid & 1;
#pragma unroll
            for (int sp = 0; sp < 4; ++sp) {
                const u16* base = &col[nn * COLP + sp * 8 + h2 * 4];
                float m0 = -1e30f, m1 = -1e30f, m2 = -1e30f, m3 = -1e30f;
#pragma unroll
                for (int t = 0; t < 9; ++t) {
                    uint2 v = *(const uint2*)(base + t * 32);
                    m0 = fmaxf(m0, lo_bf(v.x)); m1 = fmaxf(m1, hi_bf(v.x));
                    m2 = fmaxf(m2, lo_bf(v.y)); m3 = fmaxf(m3, hi_bf(v.y));
                }
                int cb = round * 32 + sp * 8 + h2 * 4;
                att_acc += att_w[cb] * m0 + att_w[cb + 1] * m1 + att_w[cb + 2] * m2 + att_w[cb + 3] * m3;
            }
        }

        // MFMA phase: no internal barriers (col stable; A streamed from L2)
#pragma unroll
        for (int ts = 0; ts < 9; ++ts) {
            int kc = round * 9 + ts;
            bf16x8 bf[2];
#pragma unroll
            for (int nt = 0; nt < 2; ++nt)
                bf[nt] = *(const bf16x8*)&col[(nt * 16 + l15) * COLP + ts * 32 + kb * 8];
#pragma unroll
            for (int mt = 0; mt < 2; ++mt) {
                uint4 a = pw[(size_t)kc * 1024 + (wm + mt * 16 + l15) * 4 + kb];
                bf16x8 af = __builtin_bit_cast(bf16x8, a);
#pragma unroll
                for (int nt = 0; nt < 2; ++nt)
                    acc[mt][nt] = __builtin_amdgcn_mfma_f32_16x16x32_bf16(af, bf[nt], acc[mt][nt], 0, 0, 0);
            }
        }
    }

    // finalize attention (wave 0), broadcast via LDS
    if (tid < 64) {
        float v = att_acc + __shfl_xor(att_acc, 1);
        if ((tid & 1) == 0) s_att[tid >> 1] = 1.f / (1.f + expf(-(v + att_b[0])));
    }
    __syncthreads();

    float attn[2];
#pragma unroll
    for (int nt = 0; nt < 2; ++nt) attn[nt] = s_att[nt * 16 + l15];

    // epilogue: scale by att, write out, GN partial sums (m-group = m>>3)
#pragma unroll
    for (int mt = 0; mt < 2; ++mt) {
        float s1 = 0.f, s2 = 0.f;
#pragma unroll
        for (int nt = 0; nt < 2; ++nt)
#pragma unroll
            for (int r = 0; r < 4; ++r) {
                float v = acc[mt][nt][r] * attn[nt];
                int m = wm + mt * 16 + kb * 4 + r;
                outp[(((size_t)(b * CT + m)) << 12) + h * 64 + n0 + nt * 16 + l15] = v;
                s1 += v; s2 += v * v;
            }
#pragma unroll
        for (int d = 1; d <= 16; d <<= 1) {
            s1 += __shfl_xor(s1, d);
            s2 += __shfl_xor(s2, d);
        }
        if ((lane & 31) == 0) {        // lanes 0 (kb 0/1) and 32 (kb 2/3)
            int gidx = w * 4 + mt * 2 + (kb >> 1);
            gnpart[blockIdx.x * 64 + gidx * 2] = s1;
            gnpart[blockIdx.x * 64 + gidx * 2 + 1] = s2;
        }
    }
}

// Fused GroupNorm: one block per (b,g); reduce 128 partial pairs -> stats -> normalize 32768 floats.
__global__ __launch_bounds__(256) void k_gn(const float* __restrict__ gnpart, const float* __restrict__ gamma,
                                            const float* __restrict__ beta, float* __restrict__ outp)
{
    __shared__ float rs1[128], rs2[128];
    __shared__ float s_stat[2];
    int bg = blockIdx.x;               // b = bg>>5, g = bg&31
    int b = bg >> 5, g = bg & 31;
    int tid = threadIdx.x;
    if (tid < 128) {
        int blk = (b * 64 + (tid >> 1)) * 2 + (tid & 1);
        rs1[tid] = gnpart[blk * 64 + g * 2];
        rs2[tid] = gnpart[blk * 64 + g * 2 + 1];
    }
    __syncthreads();
    if (tid < 64) {
        float a = rs1[tid] + rs1[tid + 64];
        float c = rs2[tid] + rs2[tid + 64];
#pragma unroll
        for (int d = 1; d <= 32; d <<= 1) {
            a += __shfl_xor(a, d);
            c += __shfl_xor(c, d);
        }
        if (tid == 0) {
            float mean = a * (1.f / 32768.f);
            float var = c * (1.f / 32768.f) - mean * mean;
            s_stat[0] = mean;
            s_stat[1] = rsqrtf(var + 1e-5f);
        }
    }
    __syncthreads();
    float mean = s_stat[0], rstd = s_stat[1];
    float4* p4 = (float4*)(outp + ((size_t)(b * CT + g * 8) << 12));
    for (int i = tid; i < 8192; i += 256) {
        int c = g * 8 + (i >> 10);
        float ga = gamma[c], be = beta[c];
        float4 v = p4[i];
        float4 r;
        r.x = fmaxf((v.x - mean) * rstd * ga + be, 0.f);
        r.y = fmaxf((v.y - mean) * rstd * ga + be, 0.f);
        r.z = fmaxf((v.z - mean) * rstd * ga + be, 0.f);
        r.w = fmaxf((v.w - mean) * rstd * ga + be, 0.f);
        p4[i] = r;
    }
}

extern "C" void kernel_launch(void* const* d_in, const int* in_sizes, int n_in,
                              void* d_out, int out_size, void* d_ws, size_t ws_size,
                              hipStream_t stream)
{
    const float* x = (const float*)d_in[0];
    const float* off = (const float*)d_in[1];
    const float* wgt = (const float*)d_in[2];
    const float* attw = (const float*)d_in[3];
    const float* attb = (const float*)d_in[4];
    const float* gamma = (const float*)d_in[5];
    const float* beta = (const float*)d_in[6];
    float* outp = (float*)d_out;

    char* ws = (char*)d_ws;
    uint4* xi = (uint4*)ws;                          // 524288 uint4 = 8.39 MB
    uint4* pw = (uint4*)(ws + 8388608);              // 73728 uint4 = 1.18 MB
    float* gnpart = (float*)(ws + 9568256);          // 512*64 f32 = 128 KB

    k_prep<<<dim3(2336), dim3(256), 0, stream>>>(x, xi, wgt, pw);
    k_main<<<dim3(512), dim3(512), 0, stream>>>(xi, off, pw, attw, attb, outp, gnpart);
    k_gn<<<dim3(128), dim3(256), 0, stream>>>(gnpart, gamma, beta, outp);
}